// Round 8
// baseline (143.713 us; speedup 1.0000x reference)
//
#include <hip/hip_runtime.h>
#include <hip/hip_bf16.h>
#include <math.h>

#define NN 128
#define TRI 8256          // 128*129/2
#define BATCH 2048
#define M_L 10
#define KAPPA 0.276f
#define LDL 136           // padded row stride (fp16): 17 quads/row, 16B-aligned rows

using half8  = __attribute__((ext_vector_type(8))) _Float16;  // MFMA A/B frag (4 VGPRs)
using half2v = __attribute__((ext_vector_type(2))) _Float16;
using f32x4  = __attribute__((ext_vector_type(4))) float;     // MFMA C/D frag

static __device__ inline float dot2h(unsigned m, unsigned y, float c) {
#if __has_builtin(__builtin_amdgcn_fdot2)
    return __builtin_amdgcn_fdot2(__builtin_bit_cast(half2v, m),
                                  __builtin_bit_cast(half2v, y), c, false);
#else
    half2v a = __builtin_bit_cast(half2v, m), b = __builtin_bit_cast(half2v, y);
    return c + (float)a.x * (float)b.x + (float)a.y * (float)b.y;
#endif
}

// ---------------------------------------------------------------------------
// Kernel 1: ONE WAVE PER BATCH, barrier-free Lanczos loop.
// Block = 4 waves = 4 batches. Setup (per batch q, all 256 threads):
//   zero Lsq -> stage L fp16 (coalesced) -> M = L*L^T via MFMA (in-place,
//   R7-verified) -> wave q copies its M rows to VGPRs (lane l: rows 2l,2l+1).
// Loop (wave-synchronous, ZERO barriers): dd via shuffles, y broadcast via
// 64-uint wave-local LDS scratch, 128 fp16-dot2/lane, 3 butterfly reductions.
// ---------------------------------------------------------------------------
__global__ __launch_bounds__(256, 2) void lanczos_kernel(
    const float* __restrict__ net_out,
    const float* __restrict__ U1,
    const float* __restrict__ v_in,
    float* __restrict__ ab_out)   // [BATCH][20]
{
    __shared__ __align__(16) _Float16 Lsq[128 * LDL];   // 34KB: L then M (per setup batch)
    __shared__ __align__(16) unsigned yscr[4][64];      // per-wave y broadcast scratch

    const int t = threadIdx.x;
    const int lane = t & 63;
    const int w = t >> 6;              // wave id 0..3
    const int myb = blockIdx.x * 4 + w;

    // register state for MY batch
    unsigned m0[64], m1[64];           // M rows 2*lane, 2*lane+1 (fp16 pairs)
    float x0 = 0.f, x1 = 0.f, p0 = 0.f, p1 = 0.f, beta = 0.f;
    float u0c = 0.f, u1c = 0.f, u0m = 0.f, u1m = 0.f;

    // =================== setup: 4 batches sequentially ===================
    for (int q = 0; q < 4; q++) {
        const int b = blockIdx.x * 4 + q;

        // ---- zero Lsq ----
        {
            unsigned long long* z = (unsigned long long*)Lsq;
            #pragma unroll
            for (int k = t; k < 128 * LDL / 4; k += 256) z[k] = 0ULL;
        }
        __syncthreads();

        // ---- stage L: coalesced float4 reads of packed tril, scatter fp16 ----
        {
            const float4* src4 = (const float4*)(net_out + (size_t)b * TRI);
            for (int qd = t; qd < TRI / 4; qd += 256) {
                float4 f = src4[qd];
                int e = 4 * qd;
                int r = (int)((sqrtf(8.0f * (float)e + 1.0f) - 1.0f) * 0.5f);
                while ((r + 1) * (r + 2) / 2 <= e) r++;
                while (r * (r + 1) / 2 > e) r--;
                int c = e - r * (r + 1) / 2;
                Lsq[r * LDL + c] = (_Float16)f.x;
                c++; if (c > r) { r++; c = 0; }
                Lsq[r * LDL + c] = (_Float16)f.y;
                c++; if (c > r) { r++; c = 0; }
                Lsq[r * LDL + c] = (_Float16)f.z;
                c++; if (c > r) { r++; c = 0; }
                Lsq[r * LDL + c] = (_Float16)f.w;
            }
        }
        __syncthreads();

        // ---- GEMM: M = L * L^T (16x16x32 f16 MFMA; wave w: bands w, w+4) ----
        {
            const int m = lane & 15;
            const int g = lane >> 4;
            f32x4 acc[2][8];
            #pragma unroll
            for (int bi = 0; bi < 2; bi++)
                #pragma unroll
                for (int j = 0; j < 8; j++) acc[bi][j] = (f32x4){0.f, 0.f, 0.f, 0.f};
            const int band0 = w, band1 = w + 4;
            #pragma unroll
            for (int kc = 0; kc < 4; kc++) {
                const int col = kc * 32 + g * 8;
                half8 a0 = *(const half8*)&Lsq[(16 * band0 + m) * LDL + col];
                half8 a1 = *(const half8*)&Lsq[(16 * band1 + m) * LDL + col];
                #pragma unroll
                for (int j = 0; j < 8; j++) {
                    half8 bfr = *(const half8*)&Lsq[(16 * j + m) * LDL + col];
                    acc[0][j] = __builtin_amdgcn_mfma_f32_16x16x32_f16(a0, bfr, acc[0][j], 0, 0, 0);
                    acc[1][j] = __builtin_amdgcn_mfma_f32_16x16x32_f16(a1, bfr, acc[1][j], 0, 0, 0);
                }
            }
            __syncthreads();   // ALL Lsq reads complete before in-place overwrite

            #pragma unroll
            for (int bi = 0; bi < 2; bi++) {
                const int band = (bi == 0) ? band0 : band1;
                #pragma unroll
                for (int j = 0; j < 8; j++) {
                    f32x4 a = acc[bi][j];
                    half2v p01 = {(_Float16)a[0], (_Float16)a[1]};
                    half2v p23 = {(_Float16)a[2], (_Float16)a[3]};
                    uint2 pk;
                    pk.x = __builtin_bit_cast(unsigned, p01);
                    pk.y = __builtin_bit_cast(unsigned, p23);
                    *(uint2*)&Lsq[(16 * j + m) * LDL + 16 * band + 4 * g] = pk;
                }
            }
        }
        __syncthreads();   // M ready in Lsq

        // ---- wave q: copy M rows to registers + load v, u ----
        if (w == q) {
            #pragma unroll
            for (int c = 0; c < 16; c++) {
                uint4 a = *(const uint4*)&Lsq[(2 * lane) * LDL + 8 * c];
                m0[4 * c] = a.x; m0[4 * c + 1] = a.y; m0[4 * c + 2] = a.z; m0[4 * c + 3] = a.w;
                uint4 bb = *(const uint4*)&Lsq[(2 * lane + 1) * LDL + 8 * c];
                m1[4 * c] = bb.x; m1[4 * c + 1] = bb.y; m1[4 * c + 2] = bb.z; m1[4 * c + 3] = bb.w;
            }
            float2 vv = *(const float2*)(v_in + (size_t)b * NN + 2 * lane);
            float s = vv.x * vv.x + vv.y * vv.y;
            #pragma unroll
            for (int o = 1; o < 64; o <<= 1) s += __shfl_xor(s, o, 64);
            float inv = 1.0f / sqrtf(s);
            x0 = vv.x * inv; x1 = vv.y * inv;
            float2 uu = *(const float2*)(U1 + (size_t)b * 128 + 2 * lane);
            u0c = uu.x; u1c = uu.y;
            u0m = __shfl(u0c, (lane + 56) & 63, 64);                 // u0 at (si-1, sj)
            u1m = __shfl(u1c, (lane & 56) | ((lane + 7) & 7), 64);   // u1 at (si, sj-1)
        }
        __syncthreads();   // protect Lsq until row-copy done
    }

    // =================== barrier-free per-wave Lanczos loop ===================
    unsigned* ys = yscr[w];
    const int l_ip = (lane + 8) & 63;                  // x[c+16]
    const int l_jp = (lane & 56) | ((lane + 1) & 7);   // x[c+2]
    const int l_im = (lane + 56) & 63;                 // x[c-16]
    const int l_jm = (lane & 56) | ((lane + 7) & 7);   // x[c-2]

    for (int it = 0; it < M_L; it++) {
        // ---- y = dd(x) via shuffles ----
        float a0 = __shfl(x0, l_ip, 64), a1 = __shfl(x1, l_ip, 64);
        float b0 = __shfl(x0, l_jp, 64), b1 = __shfl(x1, l_jp, 64);
        float c0 = __shfl(x0, l_im, 64), c1 = __shfl(x1, l_im, 64);
        float d0 = __shfl(x0, l_jm, 64), d1 = __shfl(x1, l_jm, 64);
        float y0 = x0 - KAPPA * (u0c * a0 + u1c * b0 + u0m * c0 + u1m * d0);
        float y1 = x1 - KAPPA * (u0c * a1 + u1c * b1 + u0m * c1 + u1m * d1);

        // ---- broadcast y through wave-local LDS scratch (wave-synchronous) ----
        half2v yp = {(_Float16)y0, (_Float16)y1};
        ys[lane] = __builtin_bit_cast(unsigned, yp);

        // ---- z = M . y  (rows 2l, 2l+1 from registers) ----
        float z0 = 0.f, z1 = 0.f;
        #pragma unroll
        for (int c = 0; c < 16; c++) {
            uint4 yv = *(const uint4*)&ys[4 * c];
            z0 = dot2h(m0[4 * c],     yv.x, z0);
            z1 = dot2h(m1[4 * c],     yv.x, z1);
            z0 = dot2h(m0[4 * c + 1], yv.y, z0);
            z1 = dot2h(m1[4 * c + 1], yv.y, z1);
            z0 = dot2h(m0[4 * c + 2], yv.z, z0);
            z1 = dot2h(m1[4 * c + 2], yv.z, z1);
            z0 = dot2h(m0[4 * c + 3], yv.w, z0);
            z1 = dot2h(m1[4 * c + 3], yv.w, z1);
        }

        // ---- triple butterfly reduction: alpha, |z|^2, <z,p> ----
        float s1 = z0 * x0 + z1 * x1;
        float s2 = z0 * z0 + z1 * z1;
        float s3 = z0 * p0 + z1 * p1;
        #pragma unroll
        for (int o = 1; o < 64; o <<= 1) {
            s1 += __shfl_xor(s1, o, 64);
            s2 += __shfl_xor(s2, o, 64);
            s3 += __shfl_xor(s3, o, 64);
        }

        // ---- update (alpha AND beta in one step; R7-verified identity) ----
        float alpha = s1;
        float b2 = s2 - alpha * alpha - beta * (2.0f * s3 - beta);
        float bn = sqrtf(fmaxf(b2, 0.0f));
        float w0 = z0 - alpha * x0 - beta * p0;
        float w1 = z1 - alpha * x1 - beta * p1;
        float inv = 1.0f / (bn + 1e-30f);
        p0 = x0; p1 = x1;
        x0 = w0 * inv; x1 = w1 * inv;
        beta = bn;
        if (lane == 0) {
            ab_out[(size_t)myb * 20 + it]      = alpha;
            ab_out[(size_t)myb * 20 + 10 + it] = bn;
        }
    }
}

// ---------------------------------------------------------------------------
// Kernel 2: eigen-extremes of 10x10 sym tridiagonal, ONE WAVE PER BATCH.
// 65-section with division-free fp64 Sturm sign counts (verified R2-R7).
// ---------------------------------------------------------------------------
__device__ inline int sturm_count10(const double* a, const double* off2, double x) {
    double pm = 1.0;
    double p  = a[0] - x;
    int c = (p < 0.0);
    #pragma unroll
    for (int i = 1; i < M_L; i++) {
        double pn = (a[i] - x) * p - off2[i - 1] * pm;
        c += ((pn < 0.0) != (p < 0.0));
        if (fabs(pn) > 1e150) { pn *= 1e-150; p *= 1e-150; }
        pm = p; p = pn;
    }
    return c;
}

__device__ inline double msect_smallest(const double* a, const double* off2,
                                        double lo, double hi, int K, int lane) {
    for (int round = 0; round < 4; round++) {
        double wdt = (hi - lo) * (1.0 / 65.0);
        double x = lo + wdt * (double)(lane + 1);
        int cnt = sturm_count10(a, off2, x);
        unsigned long long mask = __ballot(cnt >= K);
        if (mask == 0ULL) {
            lo = lo + wdt * 64.0;
        } else {
            int p = __ffsll(mask) - 1;
            hi = lo + wdt * (double)(p + 1);
            if (p > 0) lo = lo + wdt * (double)p;
        }
    }
    return 0.5 * (lo + hi);
}

__device__ inline double msect_window(const double* a, const double* off2,
                                      double maxabs, int lane) {
    double lo = 0.0, hi = maxabs;
    for (int round = 0; round < 4; round++) {
        double wdt = (hi - lo) * (1.0 / 65.0);
        double s = lo + wdt * (double)(lane + 1);
        int inwin = sturm_count10(a, off2, s) - sturm_count10(a, off2, -s);
        unsigned long long mask = __ballot(inwin >= 1);
        if (mask == 0ULL) {
            lo = lo + wdt * 64.0;
        } else {
            int p = __ffsll(mask) - 1;
            hi = lo + wdt * (double)(p + 1);
            if (p > 0) lo = lo + wdt * (double)p;
        }
    }
    return 0.5 * (lo + hi);
}

__global__ __launch_bounds__(256) void eig_kernel(
    const float* __restrict__ ab, float* __restrict__ contrib)
{
    const int lane = threadIdx.x & 63;
    const int b = blockIdx.x * 4 + (threadIdx.x >> 6);
    if (b >= BATCH) return;
    const float* p = ab + (size_t)b * 20;
    double a[M_L], off2[M_L - 1], offa[M_L - 1];
    #pragma unroll
    for (int i = 0; i < M_L; i++) a[i] = (double)p[i];
    #pragma unroll
    for (int i = 0; i < M_L - 1; i++) {
        double bb = (double)p[10 + i];
        offa[i] = fabs(bb);
        off2[i] = bb * bb;
    }
    double lo = 1e300, hi = -1e300;
    #pragma unroll
    for (int i = 0; i < M_L; i++) {
        double r = 0.0;
        if (i > 0) r += offa[i - 1];
        if (i < M_L - 1) r += offa[i];
        lo = fmin(lo, a[i] - r);
        hi = fmax(hi, a[i] + r);
    }
    double lmax = msect_smallest(a, off2, lo, hi, M_L, lane);
    double lmin = msect_smallest(a, off2, lo, hi, 1,   lane);
    double maxabs = fmax(fabs(lmax), fabs(lmin));
    double minabs = msect_window(a, off2, maxabs, lane);
    if (lane == 0) contrib[b] = (float)(maxabs * maxabs - minabs * minabs);
}

// ---------------------------------------------------------------------------
// Kernel 3: reduce 2048 contributions -> d_out[0] (mean)
// ---------------------------------------------------------------------------
__global__ __launch_bounds__(1024) void reduce_kernel(
    const float* __restrict__ contrib, float* __restrict__ out)
{
    __shared__ float red[16];
    int t = threadIdx.x;
    float s = contrib[t] + contrib[t + 1024];
    #pragma unroll
    for (int o = 32; o > 0; o >>= 1) s += __shfl_down(s, o, 64);
    if ((t & 63) == 0) red[t >> 6] = s;
    __syncthreads();
    if (t < 64) {
        float r = (t < 16) ? red[t] : 0.0f;
        #pragma unroll
        for (int o = 8; o > 0; o >>= 1) r += __shfl_down(r, o, 64);
        if (t == 0) out[0] = r / (float)BATCH;
    }
}

extern "C" void kernel_launch(void* const* d_in, const int* in_sizes, int n_in,
                              void* d_out, int out_size, void* d_ws, size_t ws_size,
                              hipStream_t stream) {
    const float* net_out = (const float*)d_in[0];
    const float* U1      = (const float*)d_in[1];
    const float* v       = (const float*)d_in[2];
    float* ab      = (float*)d_ws;            // BATCH*20 floats
    float* contrib = ab + (size_t)BATCH * 20; // BATCH floats

    lanczos_kernel<<<BATCH / 4, 256, 0, stream>>>(net_out, U1, v, ab);
    eig_kernel<<<BATCH / 4, 256, 0, stream>>>(ab, contrib);
    reduce_kernel<<<1, 1024, 0, stream>>>(contrib, (float*)d_out);
}

// Round 9
// 137.553 us; speedup vs baseline: 1.0448x; 1.0448x over previous
//
#include <hip/hip_runtime.h>
#include <hip/hip_bf16.h>
#include <math.h>

#define NN 128
#define TRI 8256          // 128*129/2
#define BATCH 2048
#define M_L 10
#define KAPPA 0.276f
#define LDL 136           // padded row stride (fp16): 17 quads/row, 16B-aligned rows

using half8  = __attribute__((ext_vector_type(8))) _Float16;  // MFMA A/B frag (4 VGPRs)
using half2v = __attribute__((ext_vector_type(2))) _Float16;
using f32x4  = __attribute__((ext_vector_type(4))) float;     // MFMA C/D frag

static __device__ inline float dot2h(unsigned m, unsigned y, float c) {
#if __has_builtin(__builtin_amdgcn_fdot2)
    return __builtin_amdgcn_fdot2(__builtin_bit_cast(half2v, m),
                                  __builtin_bit_cast(half2v, y), c, false);
#else
    half2v a = __builtin_bit_cast(half2v, m), b = __builtin_bit_cast(half2v, y);
    return c + (float)a.x * (float)b.x + (float)a.y * (float)b.y;
#endif
}

// ---------------------------------------------------------------------------
// Kernel 1: per-batch fused, wave-0-hub Lanczos.
// Setup (R7-verified): coalesced stage L(fp16) -> M = L*L^T via MFMA,
// in-place over L in LDS.
// Loop, 2 barriers/iter:
//   all 256 threads: half-row fp16 dot2 matvec (4 accumulators) -> part[]
//   wave 0 only (state x,p 2-per-lane in regs; R8-verified shuffle code):
//   combine part -> z, triple butterfly (alpha,|z|^2,<z,p>), update,
//   dd via shuffles, broadcast y through 64-uint LDS scratch.
// ---------------------------------------------------------------------------
__global__ __launch_bounds__(256, 4) void lanczos_kernel(
    const float* __restrict__ net_out,
    const float* __restrict__ U1,
    const float* __restrict__ v_in,
    float* __restrict__ ab_out)   // [BATCH][20]
{
    __shared__ __align__(16) _Float16 Lsq[128 * LDL];  // 34KB: L, then M (in-place)
    __shared__ __align__(16) unsigned ys[64];          // y broadcast (128 fp16)
    __shared__ __align__(16) float part[256];          // matvec half-row partials

    const int b = blockIdx.x;
    const int t = threadIdx.x;
    const int lane = t & 63;
    const int w = t >> 6;       // wave id 0..3

    // ---- zero Lsq (upper triangle + padding) ----
    {
        unsigned long long* z = (unsigned long long*)Lsq;
        #pragma unroll
        for (int k = t; k < 128 * LDL / 4; k += 256) z[k] = 0ULL;
    }
    __syncthreads();

    // ---- stage L: coalesced float4 reads of packed tril, scatter fp16 ----
    {
        const float4* src4 = (const float4*)(net_out + (size_t)b * TRI);
        for (int q = t; q < TRI / 4; q += 256) {
            float4 f = src4[q];
            int e = 4 * q;
            int r = (int)((sqrtf(8.0f * (float)e + 1.0f) - 1.0f) * 0.5f);
            while ((r + 1) * (r + 2) / 2 <= e) r++;
            while (r * (r + 1) / 2 > e) r--;
            int c = e - r * (r + 1) / 2;
            Lsq[r * LDL + c] = (_Float16)f.x;
            c++; if (c > r) { r++; c = 0; }
            Lsq[r * LDL + c] = (_Float16)f.y;
            c++; if (c > r) { r++; c = 0; }
            Lsq[r * LDL + c] = (_Float16)f.z;
            c++; if (c > r) { r++; c = 0; }
            Lsq[r * LDL + c] = (_Float16)f.w;
        }
    }
    __syncthreads();

    // ---- GEMM: M = L * L^T (16x16x32 f16 MFMA; wave w: bands w, w+4) ----
    {
        const int m = lane & 15;
        const int g = lane >> 4;
        f32x4 acc[2][8];
        #pragma unroll
        for (int bi = 0; bi < 2; bi++)
            #pragma unroll
            for (int j = 0; j < 8; j++) acc[bi][j] = (f32x4){0.f, 0.f, 0.f, 0.f};
        const int band0 = w, band1 = w + 4;
        #pragma unroll
        for (int kc = 0; kc < 4; kc++) {
            const int col = kc * 32 + g * 8;
            half8 a0 = *(const half8*)&Lsq[(16 * band0 + m) * LDL + col];
            half8 a1 = *(const half8*)&Lsq[(16 * band1 + m) * LDL + col];
            #pragma unroll
            for (int j = 0; j < 8; j++) {
                half8 bfr = *(const half8*)&Lsq[(16 * j + m) * LDL + col];
                acc[0][j] = __builtin_amdgcn_mfma_f32_16x16x32_f16(a0, bfr, acc[0][j], 0, 0, 0);
                acc[1][j] = __builtin_amdgcn_mfma_f32_16x16x32_f16(a1, bfr, acc[1][j], 0, 0, 0);
            }
        }
        __syncthreads();   // ALL Lsq reads complete before in-place overwrite

        #pragma unroll
        for (int bi = 0; bi < 2; bi++) {
            const int band = (bi == 0) ? band0 : band1;
            #pragma unroll
            for (int j = 0; j < 8; j++) {
                f32x4 a = acc[bi][j];
                half2v p01 = {(_Float16)a[0], (_Float16)a[1]};
                half2v p23 = {(_Float16)a[2], (_Float16)a[3]};
                uint2 pk;
                pk.x = __builtin_bit_cast(unsigned, p01);
                pk.y = __builtin_bit_cast(unsigned, p23);
                *(uint2*)&Lsq[(16 * j + m) * LDL + 16 * band + 4 * g] = pk;
            }
        }
    }
    __syncthreads();   // M ready in Lsq

    // ---- wave-0 state init: x (2 elems/lane), gauge regs, first y ----
    float x0 = 0.f, x1 = 0.f, p0 = 0.f, p1 = 0.f, beta = 0.f;
    float u0c = 0.f, u1c = 0.f, u0m = 0.f, u1m = 0.f;
    const int l_ip = (lane + 8) & 63;                  // site (i+1, j)
    const int l_jp = (lane & 56) | ((lane + 1) & 7);   // site (i, j+1)
    const int l_im = (lane + 56) & 63;                 // site (i-1, j)
    const int l_jm = (lane & 56) | ((lane + 7) & 7);   // site (i, j-1)

    if (w == 0) {
        float2 vv = *(const float2*)(v_in + (size_t)b * NN + 2 * lane);
        float s = vv.x * vv.x + vv.y * vv.y;
        #pragma unroll
        for (int o = 1; o < 64; o <<= 1) s += __shfl_xor(s, o, 64);
        float inv = 1.0f / sqrtf(s);
        x0 = vv.x * inv; x1 = vv.y * inv;
        float2 uu = *(const float2*)(U1 + (size_t)b * 128 + 2 * lane);
        u0c = uu.x; u1c = uu.y;
        u0m = __shfl(u0c, l_im, 64);   // u0 at (i-1, j)
        u1m = __shfl(u1c, l_jm, 64);   // u1 at (i, j-1)

        // first y = dd(x)
        float a0 = __shfl(x0, l_ip, 64), a1 = __shfl(x1, l_ip, 64);
        float b0 = __shfl(x0, l_jp, 64), b1 = __shfl(x1, l_jp, 64);
        float c0 = __shfl(x0, l_im, 64), c1 = __shfl(x1, l_im, 64);
        float d0 = __shfl(x0, l_jm, 64), d1 = __shfl(x1, l_jm, 64);
        float y0 = x0 - KAPPA * (u0c * a0 + u1c * b0 + u0m * c0 + u1m * d0);
        float y1 = x1 - KAPPA * (u0c * a1 + u1c * b1 + u0m * c1 + u1m * d1);
        half2v yp = {(_Float16)y0, (_Float16)y1};
        ys[lane] = __builtin_bit_cast(unsigned, yp);
    }
    __syncthreads();   // ys ready

    // =================== loop: 2 barriers per iteration ===================
    const int r = t & 127, h = t >> 7;
    const uint4* M4 = (const uint4*)&Lsq[r * LDL + 64 * h];
    const uint4* Y4 = (const uint4*)&ys[32 * h];

    for (int it = 0; it < M_L; it++) {
        // ---- all threads: half-row matvec, 4 accumulators ----
        {
            float aA = 0.f, aB = 0.f, aC = 0.f, aD = 0.f;
            #pragma unroll
            for (int c = 0; c < 8; c += 4) {
                uint4 m_0 = M4[c],     y_0 = Y4[c];
                uint4 m_1 = M4[c + 1], y_1 = Y4[c + 1];
                uint4 m_2 = M4[c + 2], y_2 = Y4[c + 2];
                uint4 m_3 = M4[c + 3], y_3 = Y4[c + 3];
                aA = dot2h(m_0.x, y_0.x, aA); aA = dot2h(m_0.y, y_0.y, aA);
                aA = dot2h(m_0.z, y_0.z, aA); aA = dot2h(m_0.w, y_0.w, aA);
                aB = dot2h(m_1.x, y_1.x, aB); aB = dot2h(m_1.y, y_1.y, aB);
                aB = dot2h(m_1.z, y_1.z, aB); aB = dot2h(m_1.w, y_1.w, aB);
                aC = dot2h(m_2.x, y_2.x, aC); aC = dot2h(m_2.y, y_2.y, aC);
                aC = dot2h(m_2.z, y_2.z, aC); aC = dot2h(m_2.w, y_2.w, aC);
                aD = dot2h(m_3.x, y_3.x, aD); aD = dot2h(m_3.y, y_3.y, aD);
                aD = dot2h(m_3.z, y_3.z, aD); aD = dot2h(m_3.w, y_3.w, aD);
            }
            part[t] = (aA + aB) + (aC + aD);
        }
        __syncthreads();   // B1: part ready

        // ---- wave 0: combine, reduce, update, dd, broadcast y ----
        if (w == 0) {
            float2 pa = *(const float2*)&part[2 * lane];
            float2 pb = *(const float2*)&part[128 + 2 * lane];
            float z0 = pa.x + pb.x;     // z[2*lane]
            float z1 = pa.y + pb.y;     // z[2*lane+1]

            float s1 = z0 * x0 + z1 * x1;
            float s2 = z0 * z0 + z1 * z1;
            float s3 = z0 * p0 + z1 * p1;
            #pragma unroll
            for (int o = 1; o < 64; o <<= 1) {
                s1 += __shfl_xor(s1, o, 64);
                s2 += __shfl_xor(s2, o, 64);
                s3 += __shfl_xor(s3, o, 64);
            }
            float alpha = s1;
            float b2 = s2 - alpha * alpha - beta * (2.0f * s3 - beta);
            float bn = sqrtf(fmaxf(b2, 0.0f));
            float w0 = z0 - alpha * x0 - beta * p0;
            float w1 = z1 - alpha * x1 - beta * p1;
            float inv = 1.0f / (bn + 1e-30f);
            p0 = x0; p1 = x1;
            x0 = w0 * inv; x1 = w1 * inv;
            beta = bn;
            if (lane == 0) {
                ab_out[(size_t)b * 20 + it]      = alpha;
                ab_out[(size_t)b * 20 + 10 + it] = bn;
            }

            // dd for next iteration
            float a0 = __shfl(x0, l_ip, 64), a1 = __shfl(x1, l_ip, 64);
            float b0 = __shfl(x0, l_jp, 64), b1 = __shfl(x1, l_jp, 64);
            float c0 = __shfl(x0, l_im, 64), c1 = __shfl(x1, l_im, 64);
            float d0 = __shfl(x0, l_jm, 64), d1 = __shfl(x1, l_jm, 64);
            float y0 = x0 - KAPPA * (u0c * a0 + u1c * b0 + u0m * c0 + u1m * d0);
            float y1 = x1 - KAPPA * (u0c * a1 + u1c * b1 + u0m * c1 + u1m * d1);
            half2v yp = {(_Float16)y0, (_Float16)y1};
            ys[lane] = __builtin_bit_cast(unsigned, yp);
        }
        __syncthreads();   // B2: ys ready for next matvec
    }
}

// ---------------------------------------------------------------------------
// Kernel 2: eigen-extremes of 10x10 sym tridiagonal, ONE WAVE PER BATCH.
// 65-section with division-free fp64 Sturm sign counts (verified R2-R8).
// ---------------------------------------------------------------------------
__device__ inline int sturm_count10(const double* a, const double* off2, double x) {
    double pm = 1.0;
    double p  = a[0] - x;
    int c = (p < 0.0);
    #pragma unroll
    for (int i = 1; i < M_L; i++) {
        double pn = (a[i] - x) * p - off2[i - 1] * pm;
        c += ((pn < 0.0) != (p < 0.0));
        if (fabs(pn) > 1e150) { pn *= 1e-150; p *= 1e-150; }
        pm = p; p = pn;
    }
    return c;
}

__device__ inline double msect_smallest(const double* a, const double* off2,
                                        double lo, double hi, int K, int lane) {
    for (int round = 0; round < 4; round++) {
        double wdt = (hi - lo) * (1.0 / 65.0);
        double x = lo + wdt * (double)(lane + 1);
        int cnt = sturm_count10(a, off2, x);
        unsigned long long mask = __ballot(cnt >= K);
        if (mask == 0ULL) {
            lo = lo + wdt * 64.0;
        } else {
            int p = __ffsll(mask) - 1;
            hi = lo + wdt * (double)(p + 1);
            if (p > 0) lo = lo + wdt * (double)p;
        }
    }
    return 0.5 * (lo + hi);
}

__device__ inline double msect_window(const double* a, const double* off2,
                                      double maxabs, int lane) {
    double lo = 0.0, hi = maxabs;
    for (int round = 0; round < 4; round++) {
        double wdt = (hi - lo) * (1.0 / 65.0);
        double s = lo + wdt * (double)(lane + 1);
        int inwin = sturm_count10(a, off2, s) - sturm_count10(a, off2, -s);
        unsigned long long mask = __ballot(inwin >= 1);
        if (mask == 0ULL) {
            lo = lo + wdt * 64.0;
        } else {
            int p = __ffsll(mask) - 1;
            hi = lo + wdt * (double)(p + 1);
            if (p > 0) lo = lo + wdt * (double)p;
        }
    }
    return 0.5 * (lo + hi);
}

__global__ __launch_bounds__(256) void eig_kernel(
    const float* __restrict__ ab, float* __restrict__ contrib)
{
    const int lane = threadIdx.x & 63;
    const int b = blockIdx.x * 4 + (threadIdx.x >> 6);
    if (b >= BATCH) return;
    const float* p = ab + (size_t)b * 20;
    double a[M_L], off2[M_L - 1], offa[M_L - 1];
    #pragma unroll
    for (int i = 0; i < M_L; i++) a[i] = (double)p[i];
    #pragma unroll
    for (int i = 0; i < M_L - 1; i++) {
        double bb = (double)p[10 + i];
        offa[i] = fabs(bb);
        off2[i] = bb * bb;
    }
    double lo = 1e300, hi = -1e300;
    #pragma unroll
    for (int i = 0; i < M_L; i++) {
        double r = 0.0;
        if (i > 0) r += offa[i - 1];
        if (i < M_L - 1) r += offa[i];
        lo = fmin(lo, a[i] - r);
        hi = fmax(hi, a[i] + r);
    }
    double lmax = msect_smallest(a, off2, lo, hi, M_L, lane);
    double lmin = msect_smallest(a, off2, lo, hi, 1,   lane);
    double maxabs = fmax(fabs(lmax), fabs(lmin));
    double minabs = msect_window(a, off2, maxabs, lane);
    if (lane == 0) contrib[b] = (float)(maxabs * maxabs - minabs * minabs);
}

// ---------------------------------------------------------------------------
// Kernel 3: reduce 2048 contributions -> d_out[0] (mean)
// ---------------------------------------------------------------------------
__global__ __launch_bounds__(1024) void reduce_kernel(
    const float* __restrict__ contrib, float* __restrict__ out)
{
    __shared__ float red[16];
    int t = threadIdx.x;
    float s = contrib[t] + contrib[t + 1024];
    #pragma unroll
    for (int o = 32; o > 0; o >>= 1) s += __shfl_down(s, o, 64);
    if ((t & 63) == 0) red[t >> 6] = s;
    __syncthreads();
    if (t < 64) {
        float r = (t < 16) ? red[t] : 0.0f;
        #pragma unroll
        for (int o = 8; o > 0; o >>= 1) r += __shfl_down(r, o, 64);
        if (t == 0) out[0] = r / (float)BATCH;
    }
}

extern "C" void kernel_launch(void* const* d_in, const int* in_sizes, int n_in,
                              void* d_out, int out_size, void* d_ws, size_t ws_size,
                              hipStream_t stream) {
    const float* net_out = (const float*)d_in[0];
    const float* U1      = (const float*)d_in[1];
    const float* v       = (const float*)d_in[2];
    float* ab      = (float*)d_ws;            // BATCH*20 floats
    float* contrib = ab + (size_t)BATCH * 20; // BATCH floats

    lanczos_kernel<<<BATCH, 256, 0, stream>>>(net_out, U1, v, ab);
    eig_kernel<<<BATCH / 4, 256, 0, stream>>>(ab, contrib);
    reduce_kernel<<<1, 1024, 0, stream>>>(contrib, (float*)d_out);
}